// Round 12
// baseline (152.391 us; speedup 1.0000x reference)
//
#include <hip/hip_runtime.h>
#include <math.h>

// TTrain log-contraction, R12: 3 waves/SIMD occupancy on the slim R9 loop.
// R8-R11 post-mortem: stage1 pinned at 60-66us across pack/scalar/shape/ILP
// variants -> ~1600 cyc/product of distributed stalls per wave; only more
// resident waves can cover them. R9's structure = 84 VGPR + 64 AGPR = 148
// unified regs -> fits launch_bounds(64,3) (unlike R6's 178-reg version
// that spilled). NCHUNK=32/CLEN=32 -> grid 4096 waves fills 3/SIMD.
// Prep now uses RNE bf16 rounding (removes coherent truncation bias).
//
// Zero-shuffle phi-feedback (R4-verified): packed C regs fed as next B
// present M~=P_phi*M, phi(32Kp+8q+j)=32Kp+16*(j>>2)+4q+(j&3), baked into
// the A'/Binit tables. Renorm every 8 products (math-identical).
// 3 kernels (R7: per-WG device fences >> kernel-boundary coherence).

#define TT_S 1024
#define TT_D 64
#define NCHUNK 32
#define CLEN 32            // NCHUNK * CLEN == TT_S

typedef __attribute__((ext_vector_type(8))) short short8;     // 8 bf16
typedef __attribute__((ext_vector_type(4))) float float4v;    // MFMA C/D
typedef __attribute__((ext_vector_type(4))) unsigned uint4v;
typedef __attribute__((ext_vector_type(2))) unsigned uint2v;

static __device__ __forceinline__ short8 as_short8(uint4v u) {
    union { uint4v u; short8 s; } x; x.u = u; return x.s;
}

static __device__ __forceinline__ short bf16_rne(float f) {
    unsigned u = __float_as_uint(f);
    return (short)((u + 0x7FFFu + ((u >> 16) & 1u)) >> 16);
}

// ---------- prep: phi-permuted A' table + phi-row-permuted Binit table ----
__global__ __launch_bounds__(256) void tt_prep(
    const float* __restrict__ core, short* __restrict__ tblA,
    short* __restrict__ tblBt)
{
    const int x = blockIdx.x;
    const int l = threadIdx.x & 63, r = threadIdx.x >> 6;
    const int n = l & 15, q = l >> 4;
    const float* W = core + x * 4096;

    if (r < 2) {
        #pragma unroll
        for (int Ii = 0; Ii < 2; ++Ii) {
            const int I = 2 * r + Ii;
            #pragma unroll
            for (int Kp = 0; Kp < 2; ++Kp) {
                short8 v;
                const int row = 16 * I + n;
                const int c0 = 32 * Kp + 4 * q;
                #pragma unroll
                for (int j = 0; j < 8; ++j) {
                    const int col = c0 + 16 * (j >> 2) + (j & 3);
                    v[j] = bf16_rne(W[row * 64 + col]);
                }
                *(short8*)(tblA + ((size_t)(x * 8 + I * 2 + Kp) * 64 + l) * 8) = v;
            }
        }
    } else {
        const int Kp = r - 2;
        #pragma unroll
        for (int J = 0; J < 4; ++J) {
            short8 v;
            const int col = 16 * J + n;
            const int r0 = 32 * Kp + 4 * q;
            #pragma unroll
            for (int j = 0; j < 8; ++j) {
                const int row = r0 + 16 * (j >> 2) + (j & 3);
                v[j] = bf16_rne(W[(row)*64 + col]);
            }
            *(short8*)(tblBt + ((size_t)(x * 8 + Kp * 4 + J) * 64 + l) * 8) = v;
        }
    }
}

// ---------- stage 1: one wave per chunk of CLEN matrices ----------
__global__ __launch_bounds__(64, 3) void tt_stage1(
    const int* __restrict__ X, const short* __restrict__ tblA,
    const short* __restrict__ tblBt, short* __restrict__ PT,
    float* __restrict__ ln1)
{
    const int w = blockIdx.x;                  // B*NCHUNK blocks
    const int b = w / NCHUNK, chunk = w % NCHUNK;
    const int l = threadIdx.x, n = l & 15, q = l >> 4;

    // chunk indices, lane-parallel (lanes 0..31 used); clamp OOB lanes
    const int li = chunk * CLEN + l;
    const int xv = X[b * TT_S + (li < TT_S ? li : TT_S - 1)];
    #define XT(t) __builtin_amdgcn_readlane(xv, (t))

    const float4v zero = {0.f, 0.f, 0.f, 0.f};
    float4v acc[4][4];
    short8 A0[8], A1[8];
    float logn = 0.f;

    #define PK(hi, lo) __builtin_amdgcn_perm(__float_as_uint(hi),             \
                                             __float_as_uint(lo), 0x07060302u)

    #define LOAD_FRAGS(DST, TBL, XIDX)                                        \
    {   const short8* p_ = (const short8*)((TBL) + (size_t)(XIDX) * 4096) + l; \
        _Pragma("unroll")                                                     \
        for (int f_ = 0; f_ < 8; ++f_) (DST)[f_] = p_[f_ * 64]; }

    #define MFMA_TBL(ABUF, BBUF)                                              \
        _Pragma("unroll")                                                     \
        for (int I_ = 0; I_ < 4; ++I_)                                        \
            _Pragma("unroll")                                                 \
            for (int J_ = 0; J_ < 4; ++J_) {                                  \
                float4v c0_ = __builtin_amdgcn_mfma_f32_16x16x32_bf16(        \
                    (ABUF)[2 * I_ + 0], (BBUF)[J_], zero, 0, 0, 0);           \
                acc[I_][J_] = __builtin_amdgcn_mfma_f32_16x16x32_bf16(        \
                    (ABUF)[2 * I_ + 1], (BBUF)[4 + J_], c0_, 0, 0, 0);        \
            }

    // column-interleaved: pack column J's B frags (transient), then its MFMAs
    #define PROD(ABUF)                                                        \
        _Pragma("unroll")                                                     \
        for (int J_ = 0; J_ < 4; ++J_) {                                      \
            uint4v u0_, u1_;                                                  \
            u0_[0] = PK(acc[0][J_][1], acc[0][J_][0]);                        \
            u0_[1] = PK(acc[0][J_][3], acc[0][J_][2]);                        \
            u0_[2] = PK(acc[1][J_][1], acc[1][J_][0]);                        \
            u0_[3] = PK(acc[1][J_][3], acc[1][J_][2]);                        \
            u1_[0] = PK(acc[2][J_][1], acc[2][J_][0]);                        \
            u1_[1] = PK(acc[2][J_][3], acc[2][J_][2]);                        \
            u1_[2] = PK(acc[3][J_][1], acc[3][J_][0]);                        \
            u1_[3] = PK(acc[3][J_][3], acc[3][J_][2]);                        \
            const short8 bl_ = as_short8(u0_);                                \
            const short8 bh_ = as_short8(u1_);                                \
            _Pragma("unroll")                                                 \
            for (int I_ = 0; I_ < 4; ++I_) {                                  \
                float4v c0_ = __builtin_amdgcn_mfma_f32_16x16x32_bf16(        \
                    (ABUF)[2 * I_ + 0], bl_, zero, 0, 0, 0);                  \
                acc[I_][J_] = __builtin_amdgcn_mfma_f32_16x16x32_bf16(        \
                    (ABUF)[2 * I_ + 1], bh_, c0_, 0, 0, 0);                   \
            }                                                                 \
        }

    #define RENORM()                                                          \
    {   float Z_ = 0.f;                                                       \
        _Pragma("unroll")                                                     \
        for (int I_ = 0; I_ < 4; ++I_)                                        \
            _Pragma("unroll")                                                 \
            for (int J_ = 0; J_ < 4; ++J_)                                    \
                _Pragma("unroll")                                             \
                for (int r_ = 0; r_ < 4; ++r_)                                \
                    Z_ = fmaxf(Z_, fabsf(acc[I_][J_][r_]));                   \
        _Pragma("unroll")                                                     \
        for (int m_ = 32; m_; m_ >>= 1) Z_ = fmaxf(Z_, __shfl_xor(Z_, m_));   \
        logn += logf(Z_);                                                     \
        const float rZ_ = 1.0f / Z_;                                          \
        _Pragma("unroll")                                                     \
        for (int I_ = 0; I_ < 4; ++I_)                                        \
            _Pragma("unroll")                                                 \
            for (int J_ = 0; J_ < 4; ++J_)                                    \
                _Pragma("unroll")                                             \
                for (int r_ = 0; r_ < 4; ++r_) acc[I_][J_][r_] *= rZ_; }

    // init + first product (B from phi-row-permuted table)
    {
        short8 Bt[8];
        LOAD_FRAGS(Bt, tblBt, XT(CLEN - 1))
        LOAD_FRAGS(A0, tblA, XT(CLEN - 2))
        LOAD_FRAGS(A1, tblA, XT(CLEN - 3))
        MFMA_TBL(A0, Bt)
    }
    LOAD_FRAGS(A0, tblA, XT(CLEN - 4))

    #pragma unroll 1
    for (int it = 0; it < (CLEN - 2) / 2; ++it) {      // it = 0..14
        // product 2it+2 consumes A1 = A'(x[29-2it]); refill A1
        PROD(A1)
        {
            const int tn = CLEN - 5 - 2 * it;          // 27 - 2it
            LOAD_FRAGS(A1, tblA, XT(tn < 0 ? 0 : tn))
        }
        // product 2it+3 consumes A0 = A'(x[28-2it]); refill A0
        if (((2 * it + 2) & 7) == 0) RENORM()
        PROD(A0)
        {
            const int tn = CLEN - 6 - 2 * it;          // 26 - 2it
            LOAD_FRAGS(A0, tblA, XT(tn < 0 ? 0 : tn))
        }
    }

    // final renorm + write P (bf16, col-major: PT[col*64+row]) + log-norm
    {
        float Z = 0.f;
        #pragma unroll
        for (int I = 0; I < 4; ++I)
            #pragma unroll
            for (int J = 0; J < 4; ++J)
                #pragma unroll
                for (int r = 0; r < 4; ++r) Z = fmaxf(Z, fabsf(acc[I][J][r]));
        #pragma unroll
        for (int m = 32; m; m >>= 1) Z = fmaxf(Z, __shfl_xor(Z, m));
        logn += logf(Z);
        const float rZ = 1.0f / Z;
        short* base = PT + (size_t)w * 4096;
        #pragma unroll
        for (int I = 0; I < 4; ++I)
            #pragma unroll
            for (int J = 0; J < 4; ++J) {
                float4v v = acc[I][J];
                #pragma unroll
                for (int r = 0; r < 4; ++r) v[r] *= rZ;
                uint2v dd;
                dd[0] = PK(v[1], v[0]);
                dd[1] = PK(v[3], v[2]);
                *(uint2v*)(base + (16 * J + n) * 64 + 16 * I + 4 * q) = dd;
            }
        if (l == 0) ln1[w] = logn;
    }
    #undef LOAD_FRAGS
    #undef MFMA_TBL
    #undef PROD
    #undef RENORM
    #undef PK
    #undef XT
}

// ---------- stage 2: combine NCHUNK chunk matrices per batch ----------
__global__ __launch_bounds__(64, 1) void tt_stage2(
    const short* __restrict__ PT, const float* __restrict__ ln1,
    const float* __restrict__ lb, const float* __restrict__ rb,
    float* __restrict__ out)
{
    __shared__ float cb[64];
    const int b = blockIdx.x, j = threadIdx.x;

    float c = lb[j];
    float Z = fabsf(c);
    #pragma unroll
    for (int m = 32; m; m >>= 1) Z = fmaxf(Z, __shfl_xor(Z, m));
    float logn = logf(Z);
    c *= (1.0f / Z);

    float ln = (j < NCHUNK) ? ln1[b * NCHUNK + j] : 0.f;
    #pragma unroll
    for (int m = 32; m; m >>= 1) ln += __shfl_xor(ln, m);
    logn += ln;

    // lane j's column of P_k: 64 bf16 contiguous (PT col-major)
    const short* base = PT + (size_t)b * NCHUNK * 4096 + j * 64;

    short8 bufA[8], bufB[8];
    #pragma unroll
    for (int f = 0; f < 8; ++f) bufA[f] = ((const short8*)base)[f];

    #define S2_STEP(BUF)                                                      \
    {                                                                         \
        cb[j] = c;                                                            \
        asm volatile("s_waitcnt lgkmcnt(0)" ::: "memory");                    \
        float a0 = 0.f, a1 = 0.f, a2 = 0.f, a3 = 0.f;                         \
        _Pragma("unroll")                                                     \
        for (int f = 0; f < 8; ++f) {                                         \
            union { short8 s; uint4v u; } uu; uu.s = (BUF)[f];                \
            const float4v cv0 = *(const float4v*)(cb + 8 * f);                \
            const float4v cv1 = *(const float4v*)(cb + 8 * f + 4);            \
            a0 = fmaf(cv0[0], __uint_as_float(uu.u[0] << 16), a0);            \
            a1 = fmaf(cv0[1], __uint_as_float(uu.u[0] & 0xffff0000u), a1);    \
            a2 = fmaf(cv0[2], __uint_as_float(uu.u[1] << 16), a2);            \
            a3 = fmaf(cv0[3], __uint_as_float(uu.u[1] & 0xffff0000u), a3);    \
            a0 = fmaf(cv1[0], __uint_as_float(uu.u[2] << 16), a0);            \
            a1 = fmaf(cv1[1], __uint_as_float(uu.u[2] & 0xffff0000u), a1);    \
            a2 = fmaf(cv1[2], __uint_as_float(uu.u[3] << 16), a2);            \
            a3 = fmaf(cv1[3], __uint_as_float(uu.u[3] & 0xffff0000u), a3);    \
        }                                                                     \
        float cn = (a0 + a1) + (a2 + a3);                                     \
        float Zl = fabsf(cn);                                                 \
        _Pragma("unroll")                                                     \
        for (int m = 32; m; m >>= 1) Zl = fmaxf(Zl, __shfl_xor(Zl, m));       \
        logn += logf(Zl);                                                     \
        c = cn * (1.0f / Zl);                                                 \
    }

    #pragma unroll 1
    for (int k = 0; k < NCHUNK; k += 2) {
        {   const short8* p = (const short8*)(base + (size_t)(k + 1) * 4096);
            #pragma unroll
            for (int f = 0; f < 8; ++f) bufB[f] = p[f];
        }
        asm volatile("" ::: "memory");
        S2_STEP(bufA)
        {   const int kn = (k + 2 < NCHUNK) ? (k + 2) : (NCHUNK - 1);
            const short8* p = (const short8*)(base + (size_t)kn * 4096);
            #pragma unroll
            for (int f = 0; f < 8; ++f) bufA[f] = p[f];
        }
        asm volatile("" ::: "memory");
        S2_STEP(bufB)
    }
    #undef S2_STEP

    float dot = c * rb[j];
    #pragma unroll
    for (int m = 32; m; m >>= 1) dot += __shfl_xor(dot, m);
    if (j == 0) out[b] = 2.0f * (logn + logf(fabsf(dot)));
}

// ---------------- fallback (R2 kernel) if d_ws is too small ----------------
__global__ __launch_bounds__(256) void tt_transpose(
    const float* __restrict__ core, float* __restrict__ coreT)
{
    __shared__ float tile[64][65];
    const int x = blockIdx.x;
    const float* src = core + x * 4096;
    float* dst = coreT + x * 4096;
    const int r0 = threadIdx.x >> 6, cc = threadIdx.x & 63;
    #pragma unroll
    for (int k = 0; k < 16; ++k) tile[r0 + 4 * k][cc] = src[(r0 + 4 * k) * 64 + cc];
    __syncthreads();
    #pragma unroll
    for (int k = 0; k < 16; ++k) dst[(r0 + 4 * k) * 64 + cc] = tile[cc][r0 + 4 * k];
}

__global__ __launch_bounds__(64, 1) void ttrain_chain2(
    const int* __restrict__ X, const float* __restrict__ coreT,
    const float* __restrict__ lb, const float* __restrict__ rb,
    float* __restrict__ out)
{
    __shared__ float cbuf[2][64];
    const int b = blockIdx.x, j = threadIdx.x;
    const int* Xrow = X + b * TT_S;
    float c = lb[j];
    float Z = fabsf(c);
    #pragma unroll
    for (int m = 32; m; m >>= 1) Z = fmaxf(Z, __shfl_xor(Z, m));
    float logn = logf(Z);
    c *= (1.0f / Z);
    const float* colbase = coreT + j * 64;
    int xs_cur = Xrow[j];
    int xs_nxt = Xrow[64 + j];
    float4 wA[16], wB[16];
    {
        const int x0 = Xrow[0];
        const float4* p = (const float4*)(colbase + x0 * 4096);
        #pragma unroll
        for (int k = 0; k < 16; ++k) wA[k] = p[k];
    }
    #define TT_STEP(WCUR, WNXT, SLOT, XNEXT, T)                              \
    {                                                                        \
        cbuf[SLOT][j] = c;                                                   \
        {                                                                    \
            const float4* pre = (const float4*)(colbase + (XNEXT) * 4096);   \
            _Pragma("unroll")                                                \
            for (int k = 0; k < 16; ++k) WNXT[k] = pre[k];                   \
        }                                                                    \
        asm volatile("s_waitcnt lgkmcnt(0)" ::: "memory");                   \
        float a0 = 0.f, a1 = 0.f, a2 = 0.f, a3 = 0.f;                        \
        const float4* cb2 = (const float4*)cbuf[SLOT];                       \
        _Pragma("unroll")                                                    \
        for (int k = 0; k < 16; ++k) {                                       \
            float4 cv = cb2[k];                                              \
            a0 = fmaf(cv.x, WCUR[k].x, a0);                                  \
            a1 = fmaf(cv.y, WCUR[k].y, a1);                                  \
            a2 = fmaf(cv.z, WCUR[k].z, a2);                                  \
            a3 = fmaf(cv.w, WCUR[k].w, a3);                                  \
        }                                                                    \
        float cn = (a0 + a1) + (a2 + a3);                                    \
        if (((T) & 7) == 7) {                                                \
            float Zl = fabsf(cn);                                            \
            _Pragma("unroll")                                                \
            for (int m = 32; m; m >>= 1) Zl = fmaxf(Zl, __shfl_xor(Zl, m));  \
            logn += logf(Zl);                                                \
            cn *= (1.0f / Zl);                                               \
        }                                                                    \
        c = cn;                                                              \
    }
    for (int tc = 0; tc < TT_S; tc += 64) {
        #pragma unroll 1
        for (int u = 0; u < 64; u += 2) {
            const int x1 = __builtin_amdgcn_readlane(xs_cur, u + 1);
            TT_STEP(wA, wB, 0, x1, tc + u)
            const int src2 = (u + 2 < 64) ? xs_cur : xs_nxt;
            const int x2 = __builtin_amdgcn_readlane(src2, (u + 2) & 63);
            TT_STEP(wB, wA, 1, x2, tc + u + 1)
        }
        xs_cur = xs_nxt;
        const int nc = tc + 128;
        xs_nxt = Xrow[((nc < TT_S) ? nc : 0) + j];
    }
    #undef TT_STEP
    float dot = c * rb[j];
    #pragma unroll
    for (int m = 32; m; m >>= 1) dot += __shfl_xor(dot, m);
    if (j == 0) out[b] = 2.0f * (logn + logf(fabsf(dot)));
}

extern "C" void kernel_launch(void* const* d_in, const int* in_sizes, int n_in,
                              void* d_out, int out_size, void* d_ws, size_t ws_size,
                              hipStream_t stream) {
    const int*   X    = (const int*)d_in[0];    // [B, S] int32
    const float* core = (const float*)d_in[1];  // [d, D, D] fp32
    const float* lb   = (const float*)d_in[2];  // [D]
    const float* rb   = (const float*)d_in[3];  // [D]
    float* out = (float*)d_out;                 // [B]

    const int B = in_sizes[0] / TT_S;
    const size_t tblBytes = (size_t)64 * 8 * 64 * 8 * sizeof(short);     // 512KB each
    const size_t ptBytes  = (size_t)B * NCHUNK * 4096 * sizeof(short);   // 32MB @B=128
    const size_t lnBytes  = (size_t)B * NCHUNK * sizeof(float);
    const size_t need = 2 * tblBytes + ptBytes + lnBytes;

    if (ws_size >= need) {
        char* w = (char*)d_ws;
        short* tblA  = (short*)w;
        short* tblBt = (short*)(w + tblBytes);
        short* PT    = (short*)(w + 2 * tblBytes);
        float* ln1   = (float*)(w + 2 * tblBytes + ptBytes);
        tt_prep<<<64, 256, 0, stream>>>(core, tblA, tblBt);
        tt_stage1<<<B * NCHUNK, 64, 0, stream>>>(X, tblA, tblBt, PT, ln1);
        tt_stage2<<<B, 64, 0, stream>>>(PT, ln1, lb, rb, out);
    } else if (ws_size >= (size_t)64 * 4096 * sizeof(float)) {
        float* coreT = (float*)d_ws;
        tt_transpose<<<64, 256, 0, stream>>>(core, coreT);
        ttrain_chain2<<<B, TT_D, 0, stream>>>(X, coreT, lb, rb, out);
    }
}

// Round 13
// 132.362 us; speedup vs baseline: 1.1513x; 1.1513x over previous
//
#include <hip/hip_runtime.h>
#include <math.h>

// TTrain log-contraction, R13 = R8 best config + wave phase-stagger probe.
//
// R8-R12 post-mortem: stage1 flat at 60-66us / MfmaUtil 44-48% across pack
// structure, scalar chain, MFMA shape, in-wave ILP, and occupancy -> the
// one consistent mechanism is PHASE-LOCKED waves: identical burst(620cyc
// MFMA)/idle(pack+load) sequences, round-robin pipe service keeps waves
// aligned, so all waves idle together -> util ~ burst/(burst+idle) ~ 50%
// regardless of wave count. R13 probe: stagger block start phases by
// (blockIdx&3) x s_sleep(9) (~580cyc each) so co-resident waves run
// anti-phase; one wave's MFMA burst fills the other's idle.
//
// Stage1 (R8 config, best: 61.2us): 16 chunks of 64/batch, 2048 waves @
// 2/SIMD, zero-shuffle phi-feedback (packed C regs fed as next B present
// M~=P_phi*M, phi(32Kp+8q+j)=32Kp+16*(j>>2)+4q+(j&3), baked into tables),
// double-VGPR A prefetch, column-interleaved pack->MFMA, renorm every 8.
// Prep: RNE bf16 (R12). Stage2: bf16 PT, double-buffered.
// 3 kernels (R7: per-WG device fences >> kernel-boundary coherence).

#define TT_S 1024
#define TT_D 64
#define NCHUNK 16
#define CLEN 64            // NCHUNK * CLEN == TT_S

typedef __attribute__((ext_vector_type(8))) short short8;     // 8 bf16
typedef __attribute__((ext_vector_type(4))) float float4v;    // MFMA C/D
typedef __attribute__((ext_vector_type(4))) unsigned uint4v;
typedef __attribute__((ext_vector_type(2))) unsigned uint2v;

static __device__ __forceinline__ short8 as_short8(uint4v u) {
    union { uint4v u; short8 s; } x; x.u = u; return x.s;
}

static __device__ __forceinline__ short bf16_rne(float f) {
    unsigned u = __float_as_uint(f);
    return (short)((u + 0x7FFFu + ((u >> 16) & 1u)) >> 16);
}

// ---------- prep: phi-permuted A' table + phi-row-permuted Binit table ----
__global__ __launch_bounds__(256) void tt_prep(
    const float* __restrict__ core, short* __restrict__ tblA,
    short* __restrict__ tblBt)
{
    const int x = blockIdx.x;
    const int l = threadIdx.x & 63, r = threadIdx.x >> 6;
    const int n = l & 15, q = l >> 4;
    const float* W = core + x * 4096;

    if (r < 2) {
        #pragma unroll
        for (int Ii = 0; Ii < 2; ++Ii) {
            const int I = 2 * r + Ii;
            #pragma unroll
            for (int Kp = 0; Kp < 2; ++Kp) {
                short8 v;
                const int row = 16 * I + n;
                const int c0 = 32 * Kp + 4 * q;
                #pragma unroll
                for (int j = 0; j < 8; ++j) {
                    const int col = c0 + 16 * (j >> 2) + (j & 3);
                    v[j] = bf16_rne(W[row * 64 + col]);
                }
                *(short8*)(tblA + ((size_t)(x * 8 + I * 2 + Kp) * 64 + l) * 8) = v;
            }
        }
    } else {
        const int Kp = r - 2;
        #pragma unroll
        for (int J = 0; J < 4; ++J) {
            short8 v;
            const int col = 16 * J + n;
            const int r0 = 32 * Kp + 4 * q;
            #pragma unroll
            for (int j = 0; j < 8; ++j) {
                const int row = r0 + 16 * (j >> 2) + (j & 3);
                v[j] = bf16_rne(W[row * 64 + col]);
            }
            *(short8*)(tblBt + ((size_t)(x * 8 + Kp * 4 + J) * 64 + l) * 8) = v;
        }
    }
}

// ---------- stage 1: one wave per chunk of 64 matrices ----------
__global__ __launch_bounds__(64, 2) void tt_stage1(
    const int* __restrict__ X, const short* __restrict__ tblA,
    const short* __restrict__ tblBt, short* __restrict__ PT,
    float* __restrict__ ln1)
{
    // phase stagger: de-phase co-resident waves' burst/idle cycles
    {
        const int ph = blockIdx.x & 3;
        if (ph > 0) __builtin_amdgcn_s_sleep(9);
        if (ph > 1) __builtin_amdgcn_s_sleep(9);
        if (ph > 2) __builtin_amdgcn_s_sleep(9);
    }

    const int w = blockIdx.x;
    const int b = w >> 4, chunk = w & 15;
    const int l = threadIdx.x, n = l & 15, q = l >> 4;

    // all 64 chunk indices, lane-parallel; per-product via v_readlane
    const int xv = X[b * TT_S + chunk * CLEN + l];
    #define XT(t) __builtin_amdgcn_readlane(xv, (t))

    const float4v zero = {0.f, 0.f, 0.f, 0.f};
    float4v acc[4][4];
    short8 A0[8], A1[8];
    float logn = 0.f;

    #define PK(hi, lo) __builtin_amdgcn_perm(__float_as_uint(hi),             \
                                             __float_as_uint(lo), 0x07060302u)

    #define LOAD_FRAGS(DST, TBL, XIDX)                                        \
    {   const short8* p_ = (const short8*)((TBL) + (size_t)(XIDX) * 4096) + l; \
        _Pragma("unroll")                                                     \
        for (int f_ = 0; f_ < 8; ++f_) (DST)[f_] = p_[f_ * 64]; }

    #define MFMA_TBL(ABUF, BBUF)                                              \
        _Pragma("unroll")                                                     \
        for (int I_ = 0; I_ < 4; ++I_)                                        \
            _Pragma("unroll")                                                 \
            for (int J_ = 0; J_ < 4; ++J_) {                                  \
                float4v c0_ = __builtin_amdgcn_mfma_f32_16x16x32_bf16(        \
                    (ABUF)[2 * I_ + 0], (BBUF)[J_], zero, 0, 0, 0);           \
                acc[I_][J_] = __builtin_amdgcn_mfma_f32_16x16x32_bf16(        \
                    (ABUF)[2 * I_ + 1], (BBUF)[4 + J_], c0_, 0, 0, 0);        \
            }

    // column-interleaved: pack column J's B frags (transient), then its MFMAs
    #define PROD(ABUF)                                                        \
        _Pragma("unroll")                                                     \
        for (int J_ = 0; J_ < 4; ++J_) {                                      \
            uint4v u0_, u1_;                                                  \
            u0_[0] = PK(acc[0][J_][1], acc[0][J_][0]);                        \
            u0_[1] = PK(acc[0][J_][3], acc[0][J_][2]);                        \
            u0_[2] = PK(acc[1][J_][1], acc[1][J_][0]);                        \
            u0_[3] = PK(acc[1][J_][3], acc[1][J_][2]);                        \
            u1_[0] = PK(acc[2][J_][1], acc[2][J_][0]);                        \
            u1_[1] = PK(acc[2][J_][3], acc[2][J_][2]);                        \
            u1_[2] = PK(acc[3][J_][1], acc[3][J_][0]);                        \
            u1_[3] = PK(acc[3][J_][3], acc[3][J_][2]);                        \
            const short8 bl_ = as_short8(u0_);                                \
            const short8 bh_ = as_short8(u1_);                                \
            _Pragma("unroll")                                                 \
            for (int I_ = 0; I_ < 4; ++I_) {                                  \
                float4v c0_ = __builtin_amdgcn_mfma_f32_16x16x32_bf16(        \
                    (ABUF)[2 * I_ + 0], bl_, zero, 0, 0, 0);                  \
                acc[I_][J_] = __builtin_amdgcn_mfma_f32_16x16x32_bf16(        \
                    (ABUF)[2 * I_ + 1], bh_, c0_, 0, 0, 0);                   \
            }                                                                 \
        }

    #define RENORM()                                                          \
    {   float Z_ = 0.f;                                                       \
        _Pragma("unroll")                                                     \
        for (int I_ = 0; I_ < 4; ++I_)                                        \
            _Pragma("unroll")                                                 \
            for (int J_ = 0; J_ < 4; ++J_)                                    \
                _Pragma("unroll")                                             \
                for (int r_ = 0; r_ < 4; ++r_)                                \
                    Z_ = fmaxf(Z_, fabsf(acc[I_][J_][r_]));                   \
        _Pragma("unroll")                                                     \
        for (int m_ = 32; m_; m_ >>= 1) Z_ = fmaxf(Z_, __shfl_xor(Z_, m_));   \
        logn += logf(Z_);                                                     \
        const float rZ_ = 1.0f / Z_;                                          \
        _Pragma("unroll")                                                     \
        for (int I_ = 0; I_ < 4; ++I_)                                        \
            _Pragma("unroll")                                                 \
            for (int J_ = 0; J_ < 4; ++J_)                                    \
                _Pragma("unroll")                                             \
                for (int r_ = 0; r_ < 4; ++r_) acc[I_][J_][r_] *= rZ_; }

    // init + first product (B from phi-row-permuted table)
    {
        short8 Bt[8];
        LOAD_FRAGS(Bt, tblBt, XT(CLEN - 1))
        LOAD_FRAGS(A0, tblA, XT(CLEN - 2))
        LOAD_FRAGS(A1, tblA, XT(CLEN - 3))
        MFMA_TBL(A0, Bt)
    }
    LOAD_FRAGS(A0, tblA, XT(CLEN - 4))

    #pragma unroll 1
    for (int it = 0; it < 31; ++it) {
        // product 2it+2 (consumes A1), refill A1
        PROD(A1)
        {
            const int tn = 59 - 2 * it;
            LOAD_FRAGS(A1, tblA, XT(tn < 0 ? 0 : tn))
        }
        // product 2it+3 (consumes A0), refill A0
        if (((2 * it + 2) & 7) == 0) RENORM()
        PROD(A0)
        {
            const int tn = 58 - 2 * it;
            LOAD_FRAGS(A0, tblA, XT(tn < 0 ? 0 : tn))
        }
    }

    // final renorm + write P (bf16, col-major: PT[col*64+row]) + log-norm
    {
        float Z = 0.f;
        #pragma unroll
        for (int I = 0; I < 4; ++I)
            #pragma unroll
            for (int J = 0; J < 4; ++J)
                #pragma unroll
                for (int r = 0; r < 4; ++r) Z = fmaxf(Z, fabsf(acc[I][J][r]));
        #pragma unroll
        for (int m = 32; m; m >>= 1) Z = fmaxf(Z, __shfl_xor(Z, m));
        logn += logf(Z);
        const float rZ = 1.0f / Z;
        short* base = PT + (size_t)w * 4096;
        #pragma unroll
        for (int I = 0; I < 4; ++I)
            #pragma unroll
            for (int J = 0; J < 4; ++J) {
                float4v v = acc[I][J];
                #pragma unroll
                for (int r = 0; r < 4; ++r) v[r] *= rZ;
                uint2v dd;
                dd[0] = PK(v[1], v[0]);
                dd[1] = PK(v[3], v[2]);
                *(uint2v*)(base + (16 * J + n) * 64 + 16 * I + 4 * q) = dd;
            }
        if (l == 0) ln1[w] = logn;
    }
    #undef LOAD_FRAGS
    #undef MFMA_TBL
    #undef PROD
    #undef RENORM
    #undef PK
    #undef XT
}

// ---------- stage 2: combine NCHUNK chunk matrices per batch ----------
__global__ __launch_bounds__(64, 1) void tt_stage2(
    const short* __restrict__ PT, const float* __restrict__ ln1,
    const float* __restrict__ lb, const float* __restrict__ rb,
    float* __restrict__ out)
{
    __shared__ float cb[64];
    const int b = blockIdx.x, j = threadIdx.x;

    float c = lb[j];
    float Z = fabsf(c);
    #pragma unroll
    for (int m = 32; m; m >>= 1) Z = fmaxf(Z, __shfl_xor(Z, m));
    float logn = logf(Z);
    c *= (1.0f / Z);

    float ln = (j < NCHUNK) ? ln1[b * NCHUNK + j] : 0.f;
    #pragma unroll
    for (int m = 32; m; m >>= 1) ln += __shfl_xor(ln, m);
    logn += ln;

    // lane j's column of P_k: 64 bf16 contiguous (PT col-major)
    const short* base = PT + (size_t)b * NCHUNK * 4096 + j * 64;

    short8 bufA[8], bufB[8];
    #pragma unroll
    for (int f = 0; f < 8; ++f) bufA[f] = ((const short8*)base)[f];

    #define S2_STEP(BUF)                                                      \
    {                                                                         \
        cb[j] = c;                                                            \
        asm volatile("s_waitcnt lgkmcnt(0)" ::: "memory");                    \
        float a0 = 0.f, a1 = 0.f, a2 = 0.f, a3 = 0.f;                         \
        _Pragma("unroll")                                                     \
        for (int f = 0; f < 8; ++f) {                                         \
            union { short8 s; uint4v u; } uu; uu.s = (BUF)[f];                \
            const float4v cv0 = *(const float4v*)(cb + 8 * f);                \
            const float4v cv1 = *(const float4v*)(cb + 8 * f + 4);            \
            a0 = fmaf(cv0[0], __uint_as_float(uu.u[0] << 16), a0);            \
            a1 = fmaf(cv0[1], __uint_as_float(uu.u[0] & 0xffff0000u), a1);    \
            a2 = fmaf(cv0[2], __uint_as_float(uu.u[1] << 16), a2);            \
            a3 = fmaf(cv0[3], __uint_as_float(uu.u[1] & 0xffff0000u), a3);    \
            a0 = fmaf(cv1[0], __uint_as_float(uu.u[2] << 16), a0);            \
            a1 = fmaf(cv1[1], __uint_as_float(uu.u[2] & 0xffff0000u), a1);    \
            a2 = fmaf(cv1[2], __uint_as_float(uu.u[3] << 16), a2);            \
            a3 = fmaf(cv1[3], __uint_as_float(uu.u[3] & 0xffff0000u), a3);    \
        }                                                                     \
        float cn = (a0 + a1) + (a2 + a3);                                     \
        float Zl = fabsf(cn);                                                 \
        _Pragma("unroll")                                                     \
        for (int m = 32; m; m >>= 1) Zl = fmaxf(Zl, __shfl_xor(Zl, m));       \
        logn += logf(Zl);                                                     \
        c = cn * (1.0f / Zl);                                                 \
    }

    #pragma unroll 1
    for (int k = 0; k < NCHUNK; k += 2) {
        {   const short8* p = (const short8*)(base + (size_t)(k + 1) * 4096);
            #pragma unroll
            for (int f = 0; f < 8; ++f) bufB[f] = p[f];
        }
        asm volatile("" ::: "memory");
        S2_STEP(bufA)
        {   const int kn = (k + 2 < NCHUNK) ? (k + 2) : (NCHUNK - 1);
            const short8* p = (const short8*)(base + (size_t)kn * 4096);
            #pragma unroll
            for (int f = 0; f < 8; ++f) bufA[f] = p[f];
        }
        asm volatile("" ::: "memory");
        S2_STEP(bufB)
    }
    #undef S2_STEP

    float dot = c * rb[j];
    #pragma unroll
    for (int m = 32; m; m >>= 1) dot += __shfl_xor(dot, m);
    if (j == 0) out[b] = 2.0f * (logn + logf(fabsf(dot)));
}

// ---------------- fallback (R2 kernel) if d_ws is too small ----------------
__global__ __launch_bounds__(256) void tt_transpose(
    const float* __restrict__ core, float* __restrict__ coreT)
{
    __shared__ float tile[64][65];
    const int x = blockIdx.x;
    const float* src = core + x * 4096;
    float* dst = coreT + x * 4096;
    const int r0 = threadIdx.x >> 6, cc = threadIdx.x & 63;
    #pragma unroll
    for (int k = 0; k < 16; ++k) tile[r0 + 4 * k][cc] = src[(r0 + 4 * k) * 64 + cc];
    __syncthreads();
    #pragma unroll
    for (int k = 0; k < 16; ++k) dst[(r0 + 4 * k) * 64 + cc] = tile[cc][r0 + 4 * k];
}

__global__ __launch_bounds__(64, 1) void ttrain_chain2(
    const int* __restrict__ X, const float* __restrict__ coreT,
    const float* __restrict__ lb, const float* __restrict__ rb,
    float* __restrict__ out)
{
    __shared__ float cbuf[2][64];
    const int b = blockIdx.x, j = threadIdx.x;
    const int* Xrow = X + b * TT_S;
    float c = lb[j];
    float Z = fabsf(c);
    #pragma unroll
    for (int m = 32; m; m >>= 1) Z = fmaxf(Z, __shfl_xor(Z, m));
    float logn = logf(Z);
    c *= (1.0f / Z);
    const float* colbase = coreT + j * 64;
    int xs_cur = Xrow[j];
    int xs_nxt = Xrow[64 + j];
    float4 wA[16], wB[16];
    {
        const int x0 = Xrow[0];
        const float4* p = (const float4*)(colbase + x0 * 4096);
        #pragma unroll
        for (int k = 0; k < 16; ++k) wA[k] = p[k];
    }
    #define TT_STEP(WCUR, WNXT, SLOT, XNEXT, T)                              \
    {                                                                        \
        cbuf[SLOT][j] = c;                                                   \
        {                                                                    \
            const float4* pre = (const float4*)(colbase + (XNEXT) * 4096);   \
            _Pragma("unroll")                                                \
            for (int k = 0; k < 16; ++k) WNXT[k] = pre[k];                   \
        }                                                                    \
        asm volatile("s_waitcnt lgkmcnt(0)" ::: "memory");                   \
        float a0 = 0.f, a1 = 0.f, a2 = 0.f, a3 = 0.f;                        \
        const float4* cb2 = (const float4*)cbuf[SLOT];                       \
        _Pragma("unroll")                                                    \
        for (int k = 0; k < 16; ++k) {                                       \
            float4 cv = cb2[k];                                              \
            a0 = fmaf(cv.x, WCUR[k].x, a0);                                  \
            a1 = fmaf(cv.y, WCUR[k].y, a1);                                  \
            a2 = fmaf(cv.z, WCUR[k].z, a2);                                  \
            a3 = fmaf(cv.w, WCUR[k].w, a3);                                  \
        }                                                                    \
        float cn = (a0 + a1) + (a2 + a3);                                    \
        if (((T) & 7) == 7) {                                                \
            float Zl = fabsf(cn);                                            \
            _Pragma("unroll")                                                \
            for (int m = 32; m; m >>= 1) Zl = fmaxf(Zl, __shfl_xor(Zl, m));  \
            logn += logf(Zl);                                                \
            cn *= (1.0f / Zl);                                               \
        }                                                                    \
        c = cn;                                                              \
    }
    for (int tc = 0; tc < TT_S; tc += 64) {
        #pragma unroll 1
        for (int u = 0; u < 64; u += 2) {
            const int x1 = __builtin_amdgcn_readlane(xs_cur, u + 1);
            TT_STEP(wA, wB, 0, x1, tc + u)
            const int src2 = (u + 2 < 64) ? xs_cur : xs_nxt;
            const int x2 = __builtin_amdgcn_readlane(src2, (u + 2) & 63);
            TT_STEP(wB, wA, 1, x2, tc + u + 1)
        }
        xs_cur = xs_nxt;
        const int nc = tc + 128;
        xs_nxt = Xrow[((nc < TT_S) ? nc : 0) + j];
    }
    #undef TT_STEP
    float dot = c * rb[j];
    #pragma unroll
    for (int m = 32; m; m >>= 1) dot += __shfl_xor(dot, m);
    if (j == 0) out[b] = 2.0f * (logn + logf(fabsf(dot)));
}

extern "C" void kernel_launch(void* const* d_in, const int* in_sizes, int n_in,
                              void* d_out, int out_size, void* d_ws, size_t ws_size,
                              hipStream_t stream) {
    const int*   X    = (const int*)d_in[0];    // [B, S] int32
    const float* core = (const float*)d_in[1];  // [d, D, D] fp32
    const float* lb   = (const float*)d_in[2];  // [D]
    const float* rb   = (const float*)d_in[3];  // [D]
    float* out = (float*)d_out;                 // [B]

    const int B = in_sizes[0] / TT_S;
    const size_t tblBytes = (size_t)64 * 8 * 64 * 8 * sizeof(short);     // 512KB each
    const size_t ptBytes  = (size_t)B * NCHUNK * 4096 * sizeof(short);   // 16MB @B=128
    const size_t lnBytes  = (size_t)B * NCHUNK * sizeof(float);
    const size_t need = 2 * tblBytes + ptBytes + lnBytes;

    if (ws_size >= need) {
        char* w = (char*)d_ws;
        short* tblA  = (short*)w;
        short* tblBt = (short*)(w + tblBytes);
        short* PT    = (short*)(w + 2 * tblBytes);
        float* ln1   = (float*)(w + 2 * tblBytes + ptBytes);
        tt_prep<<<64, 256, 0, stream>>>(core, tblA, tblBt);
        tt_stage1<<<B * NCHUNK, 64, 0, stream>>>(X, tblA, tblBt, PT, ln1);
        tt_stage2<<<B, 64, 0, stream>>>(PT, ln1, lb, rb, out);
    } else if (ws_size >= (size_t)64 * 4096 * sizeof(float)) {
        float* coreT = (float*)d_ws;
        tt_transpose<<<64, 256, 0, stream>>>(core, coreT);
        ttrain_chain2<<<B, TT_D, 0, stream>>>(X, coreT, lb, rb, out);
    }
}